// Round 10
// baseline (423.549 us; speedup 1.0000x reference)
//
#include <hip/hip_runtime.h>
#include <hip/hip_bf16.h>
#include <math.h>

// GanDTI forward. B=4096, N_ATOMS=50, FEAT=40, GNN_DEPTH=3, MLP_DEPTH=2.
//
//  k_stream (round-7 control): 4096 blocks x 256 thr -> partial a256.
//  k_gnn (NEW): 1024 blocks x 256 thr = 4096 waves; ONE WAVE PER SAMPLE,
//    lane = atom row. ZERO LDS, ZERO barriers:
//      m1 (comp@Wg): row-local, Wg via uniform scalar loads (SMEM path).
//      m2 (A@h): cross-row via v_readlane (SGPR broadcast operand).
//      residual re-gathered from emb at end; mean via shfl_xor butterfly.
//  k_tail (round-8 control): 512 blocks x 256 thr, wave-specialized phase 0.

#define BATCH 4096

// ===================== k_stream =====================
__global__ __launch_bounds__(256) void k_stream(
    const float* __restrict__ A69, const float* __restrict__ W1,
    const float* __restrict__ b1, const float* __restrict__ W2,
    float* __restrict__ ws_part)
{
    __shared__ float a69s[64 * 10];
    const int tid  = threadIdx.x;
    const int lane = tid & 63, wv = tid >> 6;
    const int kc = blockIdx.x & 7, sg = blockIdx.x >> 3;
    const int s0 = sg * 8, k0 = kc * 128;
    const int c0 = lane * 4;

    float w1r[30];
    #pragma unroll
    for (int k = 0; k < 15; ++k) {
        float2 t = ((const float2*)W1)[k];
        w1r[2 * k] = t.x; w1r[2 * k + 1] = t.y;
    }
    const float b1v = b1[0];

    float acc[2][4] = {{0.f,0.f,0.f,0.f},{0.f,0.f,0.f,0.f}};

    for (int h = 0; h < 2; ++h) {
        const int base = k0 + h * 64;
        const int nrh = (1001 - base < 64) ? (1001 - base) : 64;
        if (h) __syncthreads();
        for (int idx = tid; idx < 512; idx += 256) {
            const int s = idx >> 6, rr = idx & 63;
            if (rr < nrh) {
                const float2* p = (const float2*)(A69 + ((size_t)(s0 + s) * 1001 + base + rr) * 30);
                float v = b1v;
                #pragma unroll
                for (int k = 0; k < 15; ++k) {
                    float2 q = p[k];
                    v = fmaf(q.x, w1r[2 * k], v);
                    v = fmaf(q.y, w1r[2 * k + 1], v);
                }
                a69s[rr * 10 + s] = v;
            }
        }
        __syncthreads();
        for (int k = 0; k < nrh; ++k) {
            const float a0 = a69s[k * 10 + wv * 2];
            const float a1 = a69s[k * 10 + wv * 2 + 1];
            float w2v[4];
            *(float4*)w2v = *(const float4*)(W2 + (size_t)(base + k) * 256 + c0);
            #pragma unroll
            for (int c = 0; c < 4; ++c) {
                acc[0][c] = fmaf(a0, w2v[c], acc[0][c]);
                acc[1][c] = fmaf(a1, w2v[c], acc[1][c]);
            }
        }
    }
    #pragma unroll
    for (int s = 0; s < 2; ++s)
        *(float4*)(ws_part + ((size_t)kc * BATCH + s0 + wv * 2 + s) * 256 + c0) = *(float4*)acc[s];
}

// ===================== k_gnn (register/readlane) =====================
__global__ __launch_bounds__(256, 4) void k_gnn(
    const int* __restrict__ atoms, const float* __restrict__ A,
    const float* __restrict__ emb, const float* __restrict__ Wg,
    const float* __restrict__ bg, float* __restrict__ ws_cv)
{
    const int lane = threadIdx.x & 63;
    const int wv   = threadIdx.x >> 6;
    const int b    = blockIdx.x * 4 + wv;     // sample
    const int nn   = lane < 50 ? lane : 49;   // atom row (clamped for tail lanes)
    const bool act = lane < 50;

    const int row = atoms[b * 50 + nn];
    float comp[40];
    #pragma unroll
    for (int f4 = 0; f4 < 10; ++f4) {
        float4 v = *(const float4*)(emb + row * 40 + f4 * 4);
        comp[f4 * 4 + 0] = v.x; comp[f4 * 4 + 1] = v.y;
        comp[f4 * 4 + 2] = v.z; comp[f4 * 4 + 3] = v.w;
    }

    const float* Arow = A + (size_t)b * 2500 + nn * 50;

    for (int l = 0; l < 3; ++l) {
        const float* wgl = Wg + l * 1600;
        const float* bgl = bg + l * 40;
        // ---- m1: h = leaky(comp @ Wg[l] + bg[l]) — row-local, Wg scalar ----
        float h[40];
        #pragma unroll
        for (int f = 0; f < 40; ++f) h[f] = bgl[f];
        #pragma unroll
        for (int j = 0; j < 40; ++j) {
            const float c = comp[j];
            #pragma unroll
            for (int f = 0; f < 40; ++f)
                h[f] = fmaf(c, wgl[j * 40 + f], h[f]);
        }
        #pragma unroll
        for (int f = 0; f < 40; ++f) h[f] = h[f] > 0.f ? h[f] : 0.01f * h[f];

        // ---- m2: comp += A @ h — cross-lane h via v_readlane ----
        for (int m0 = 0; m0 < 50; m0 += 10) {
            float a[10];
            #pragma unroll
            for (int t = 0; t < 10; ++t) a[t] = Arow[m0 + t];
            #pragma unroll
            for (int t = 0; t < 10; ++t) {
                const int m = m0 + t;      // uniform (SGPR) lane index
                #pragma unroll
                for (int f = 0; f < 40; ++f) {
                    const float hv = __uint_as_float(
                        __builtin_amdgcn_readlane(__float_as_uint(h[f]), m));
                    comp[f] = fmaf(a[t], hv, comp[f]);
                }
            }
        }
    }

    // + residual (re-gather emb row); zero tail lanes for the reduction
    if (act) {
        #pragma unroll
        for (int f4 = 0; f4 < 10; ++f4) {
            float4 v = *(const float4*)(emb + row * 40 + f4 * 4);
            comp[f4 * 4 + 0] += v.x; comp[f4 * 4 + 1] += v.y;
            comp[f4 * 4 + 2] += v.z; comp[f4 * 4 + 3] += v.w;
        }
    } else {
        #pragma unroll
        for (int f = 0; f < 40; ++f) comp[f] = 0.f;
    }
    // butterfly sum across all 64 lanes (tail lanes are zero)
    #pragma unroll
    for (int s = 1; s < 64; s <<= 1) {
        #pragma unroll
        for (int f = 0; f < 40; ++f)
            comp[f] += __shfl_xor(comp[f], s, 64);
    }
    if (lane == 0) {
        #pragma unroll
        for (int f4 = 0; f4 < 10; ++f4) {
            float4 v = make_float4(comp[f4 * 4] * 0.02f, comp[f4 * 4 + 1] * 0.02f,
                                   comp[f4 * 4 + 2] * 0.02f, comp[f4 * 4 + 3] * 0.02f);
            *(float4*)(ws_cv + (size_t)b * 40 + f4 * 4) = v;
        }
    }
}

// ===================== k_tail (round-8 control) =====================
__global__ __launch_bounds__(256) void k_tail(
    const float* __restrict__ protein, const float* __restrict__ b2,
    const float* __restrict__ W3, const float* __restrict__ b3,
    const float* __restrict__ Wp, const float* __restrict__ bp,
    const float* __restrict__ Watt, const float* __restrict__ batt,
    const float* __restrict__ Wm, const float* __restrict__ bm,
    const float* __restrict__ Wo, const float* __restrict__ bo,
    const float* __restrict__ ws_cv, const float* __restrict__ ws_part,
    float* __restrict__ out)
{
    const int G = 8, PC = 520;
    __shared__ float pc[8 * 520];
    __shared__ float p40s[8 * 40];
    __shared__ float phs[8 * 40];
    __shared__ float wts[8];
    __shared__ float cps[2][8 * 84];
    const int tid  = threadIdx.x;
    const int lane = tid & 63, wv = tid >> 6;
    const int b0   = blockIdx.x * G;
    const int c0   = lane * 4;

    if (wv < 2) {
        float acc[4][4];
        #pragma unroll
        for (int s = 0; s < 4; ++s)
            #pragma unroll
            for (int c = 0; c < 4; ++c) acc[s][c] = 0.f;
        const float* prot = protein + (size_t)(b0 + wv * 4) * 512;
        for (int j4 = 0; j4 < 128; ++j4) {
            float pv[4][4];
            #pragma unroll
            for (int s = 0; s < 4; ++s)
                *(float4*)pv[s] = *(const float4*)(prot + (size_t)s * 512 + j4 * 4);
            #pragma unroll
            for (int u = 0; u < 4; ++u) {
                float w3v[4];
                *(float4*)w3v = *(const float4*)(W3 + (size_t)(j4 * 4 + u) * 256 + c0);
                #pragma unroll
                for (int s = 0; s < 4; ++s)
                    #pragma unroll
                    for (int c = 0; c < 4; ++c)
                        acc[s][c] = fmaf(pv[s][u], w3v[c], acc[s][c]);
            }
        }
        float b3v[4];
        *(float4*)b3v = *(const float4*)(b3 + c0);
        #pragma unroll
        for (int s = 0; s < 4; ++s) {
            float o[4];
            #pragma unroll
            for (int c = 0; c < 4; ++c) o[c] = acc[s][c] + b3v[c];
            *(float4*)(pc + (wv * 4 + s) * PC + 256 + c0) = *(float4*)o;
        }
    } else {
        const int sbase = (wv - 2) * 4;
        float b2v[4];
        *(float4*)b2v = *(const float4*)(b2 + c0);
        #pragma unroll
        for (int s = 0; s < 4; ++s) {
            float o[4] = {b2v[0], b2v[1], b2v[2], b2v[3]};
            #pragma unroll
            for (int kc = 0; kc < 8; ++kc) {
                float pv[4];
                *(float4*)pv = *(const float4*)(ws_part + ((size_t)kc * BATCH + b0 + sbase + s) * 256 + c0);
                #pragma unroll
                for (int c = 0; c < 4; ++c) o[c] += pv[c];
            }
            *(float4*)(pc + (sbase + s) * PC + c0) = *(float4*)o;
        }
    }
    __syncthreads();

    if (tid < 40) {
        const int f8 = tid >> 3, g = tid & 7, fo = f8 * 8;
        float a8[8];
        #pragma unroll
        for (int c = 0; c < 8; ++c) a8[c] = bp[fo + c];
        for (int j4 = 0; j4 < 128; ++j4) {
            float pv[4];
            *(float4*)pv = *(float4*)(pc + g * PC + j4 * 4);
            #pragma unroll
            for (int u = 0; u < 4; ++u) {
                const int j = j4 * 4 + u;
                float wa[4], wb[4];
                *(float4*)wa = *(const float4*)(Wp + j * 40 + fo);
                *(float4*)wb = *(const float4*)(Wp + j * 40 + fo + 4);
                #pragma unroll
                for (int c = 0; c < 4; ++c) {
                    a8[c]     = fmaf(pv[u], wa[c], a8[c]);
                    a8[4 + c] = fmaf(pv[u], wb[c], a8[4 + c]);
                }
            }
        }
        *(float4*)(p40s + g * 40 + fo)     = *(float4*)a8;
        *(float4*)(p40s + g * 40 + fo + 4) = *(float4*)(a8 + 4);
    }
    __syncthreads();

    for (int it = tid; it < G * 40; it += 256) {
        const int g = it / 40, f = it - g * 40;
        float s = batt[f];
        #pragma unroll
        for (int j4 = 0; j4 < 10; ++j4) {
            float pv[4];
            *(float4*)pv = *(float4*)(p40s + g * 40 + j4 * 4);
            #pragma unroll
            for (int u = 0; u < 4; ++u)
                s = fmaf(pv[u], Watt[(j4 * 4 + u) * 40 + f], s);
        }
        phs[it] = s > 0.f ? s : 0.f;
    }
    __syncthreads();

    if (tid < G) {
        float m = 0.f;
        #pragma unroll
        for (int f4 = 0; f4 < 10; ++f4) {
            float cv[4], ph[4];
            *(float4*)cv = *(const float4*)(ws_cv + (size_t)(b0 + tid) * 40 + f4 * 4);
            *(float4*)ph = *(float4*)(phs + tid * 40 + f4 * 4);
            #pragma unroll
            for (int c = 0; c < 4; ++c) m = fmaf(cv[c], ph[c], m);
        }
        wts[tid] = tanhf(m);
    }
    __syncthreads();

    for (int it = tid; it < G * 80; it += 256) {
        const int g = it / 80, f = it - g * 80;
        const float v = (f < 40) ? ws_cv[(size_t)(b0 + g) * 40 + f]
                                 : wts[g] * phs[g * 40 + (f - 40)];
        cps[0][g * 84 + f] = v;
    }
    __syncthreads();

    int cb = 0;
    for (int l = 0; l < 2; ++l) {
        for (int it = tid; it < G * 80; it += 256) {
            const int g = it / 80, kk = it - g * 80;
            float s = bm[l * 80 + kk];
            #pragma unroll
            for (int j4 = 0; j4 < 20; ++j4) {
                float cv[4];
                *(float4*)cv = *(float4*)(cps[cb] + g * 84 + j4 * 4);
                #pragma unroll
                for (int u = 0; u < 4; ++u)
                    s = fmaf(cv[u], Wm[l * 6400 + (j4 * 4 + u) * 80 + kk], s);
            }
            cps[cb ^ 1][g * 84 + kk] = s > 0.f ? s : 0.f;
        }
        __syncthreads();
        cb ^= 1;
    }
    if (tid < G) {
        float s = bo[0];
        #pragma unroll
        for (int j4 = 0; j4 < 20; ++j4) {
            float cv[4], wo[4];
            *(float4*)cv = *(float4*)(cps[cb] + tid * 84 + j4 * 4);
            *(float4*)wo = *(const float4*)(Wo + j4 * 4);
            #pragma unroll
            for (int u = 0; u < 4; ++u) s = fmaf(cv[u], wo[u], s);
        }
        out[b0 + tid] = s;
    }
}

extern "C" void kernel_launch(void* const* d_in, const int* in_sizes, int n_in,
                              void* d_out, int out_size, void* d_ws, size_t ws_size,
                              hipStream_t stream) {
    const int*   atoms   = (const int*)d_in[0];
    const float* A       = (const float*)d_in[1];
    const float* A69     = (const float*)d_in[2];
    const float* protein = (const float*)d_in[3];
    const float* emb     = (const float*)d_in[4];
    const float* Wg      = (const float*)d_in[5];
    const float* bg      = (const float*)d_in[6];
    const float* Watt    = (const float*)d_in[7];
    const float* batt    = (const float*)d_in[8];
    const float* W1      = (const float*)d_in[9];
    const float* b1      = (const float*)d_in[10];
    const float* W2      = (const float*)d_in[11];
    const float* b2      = (const float*)d_in[12];
    const float* W3      = (const float*)d_in[13];
    const float* b3      = (const float*)d_in[14];
    const float* Wp      = (const float*)d_in[15];
    const float* bp      = (const float*)d_in[16];
    const float* Wm      = (const float*)d_in[17];
    const float* bm      = (const float*)d_in[18];
    const float* Wo      = (const float*)d_in[19];
    const float* bo      = (const float*)d_in[20];

    float* ws_cv   = (float*)d_ws;                  // [4096][40]
    float* ws_part = ws_cv + (size_t)BATCH * 40;    // [8][4096][256]
    float* outp    = (float*)d_out;

    k_stream<<<dim3(4096), dim3(256), 0, stream>>>(A69, W1, b1, W2, ws_part);
    k_gnn<<<dim3(1024), dim3(256), 0, stream>>>(atoms, A, emb, Wg, bg, ws_cv);
    k_tail<<<dim3(512), dim3(256), 0, stream>>>(
        protein, b2, W3, b3, Wp, bp, Watt, batt, Wm, bm, Wo, bo,
        ws_cv, ws_part, outp);
}

// Round 11
// 378.384 us; speedup vs baseline: 1.1194x; 1.1194x over previous
//
#include <hip/hip_runtime.h>
#include <hip/hip_bf16.h>
#include <math.h>

// GanDTI forward. B=4096, N_ATOMS=50, FEAT=40, GNN_DEPTH=3, MLP_DEPTH=2.
//
//  k_stream (round-8 control): 4096 blocks x 256 thr -> partial a256.
//  k_gnn (round-2 structure, occupancy-tuned): 4096 blocks x 256 thr (4 waves),
//    one sample/block; A[50][52]+comp[50][44]+h[50][44] in LDS = 28 KB ->
//    5 blocks/CU = 20 waves/CU (vs 8 in round 8). 2x4 tile, Wg from global.
//  k_tail (round-8 control): 512 blocks x 256 thr, wave-specialized phase 0.

#define BATCH 4096
#define SA 52
#define SC 44

// ===================== k_stream (control) =====================
__global__ __launch_bounds__(256) void k_stream(
    const float* __restrict__ A69, const float* __restrict__ W1,
    const float* __restrict__ b1, const float* __restrict__ W2,
    float* __restrict__ ws_part)
{
    __shared__ float a69s[64 * 10];
    const int tid  = threadIdx.x;
    const int lane = tid & 63, wv = tid >> 6;
    const int kc = blockIdx.x & 7, sg = blockIdx.x >> 3;
    const int s0 = sg * 8, k0 = kc * 128;
    const int c0 = lane * 4;

    float w1r[30];
    #pragma unroll
    for (int k = 0; k < 15; ++k) {
        float2 t = ((const float2*)W1)[k];
        w1r[2 * k] = t.x; w1r[2 * k + 1] = t.y;
    }
    const float b1v = b1[0];

    float acc[2][4] = {{0.f,0.f,0.f,0.f},{0.f,0.f,0.f,0.f}};

    for (int h = 0; h < 2; ++h) {
        const int base = k0 + h * 64;
        const int nrh = (1001 - base < 64) ? (1001 - base) : 64;
        if (h) __syncthreads();
        for (int idx = tid; idx < 512; idx += 256) {
            const int s = idx >> 6, rr = idx & 63;
            if (rr < nrh) {
                const float2* p = (const float2*)(A69 + ((size_t)(s0 + s) * 1001 + base + rr) * 30);
                float v = b1v;
                #pragma unroll
                for (int k = 0; k < 15; ++k) {
                    float2 q = p[k];
                    v = fmaf(q.x, w1r[2 * k], v);
                    v = fmaf(q.y, w1r[2 * k + 1], v);
                }
                a69s[rr * 10 + s] = v;
            }
        }
        __syncthreads();
        for (int k = 0; k < nrh; ++k) {
            const float a0 = a69s[k * 10 + wv * 2];
            const float a1 = a69s[k * 10 + wv * 2 + 1];
            float w2v[4];
            *(float4*)w2v = *(const float4*)(W2 + (size_t)(base + k) * 256 + c0);
            #pragma unroll
            for (int c = 0; c < 4; ++c) {
                acc[0][c] = fmaf(a0, w2v[c], acc[0][c]);
                acc[1][c] = fmaf(a1, w2v[c], acc[1][c]);
            }
        }
    }
    #pragma unroll
    for (int s = 0; s < 2; ++s)
        *(float4*)(ws_part + ((size_t)kc * BATCH + s0 + wv * 2 + s) * 256 + c0) = *(float4*)acc[s];
}

// ===================== k_gnn (round-2 structure, 28 KB LDS) =====================
__global__ __launch_bounds__(256) void k_gnn(
    const int* __restrict__ atoms, const float* __restrict__ A,
    const float* __restrict__ emb, const float* __restrict__ Wg,
    const float* __restrict__ bg, float* __restrict__ ws_cv)
{
    __shared__ float a_s[2600];    // [50][SA]
    __shared__ float comp[2200];   // [50][SC]
    __shared__ float h_s[2200];    // [50][SC]
    const int tid = threadIdx.x;
    const int b = blockIdx.x;

    for (int idx = tid; idx < 2500; idx += 256) {
        const int n = idx / 50, m = idx - n * 50;
        a_s[n * SA + m] = A[(size_t)b * 2500 + idx];
    }
    for (int idx = tid; idx < 500; idx += 256) {
        const int n = idx / 10, f4 = idx - n * 10;
        const int row = atoms[b * 50 + n];
        *(float4*)(comp + n * SC + f4 * 4) = *(const float4*)(emb + row * 40 + f4 * 4);
    }
    __syncthreads();

    float res_sum = 0.f;
    if (tid < 40) {
        for (int n = 0; n < 50; ++n) res_sum += comp[n * SC + tid];
    }

    const int np = tid / 10, fg = tid - np * 10;
    const int n0 = np * 2, f0 = fg * 4;
    const bool act = (tid < 250);

    for (int l = 0; l < 3; ++l) {
        const float* wgl = Wg + l * 1600;
        if (act) {
            // ---- m1: h = leaky(comp @ Wg[l] + bg[l]); Wg from global (L1) ----
            float bgv[4];
            *(float4*)bgv = *(const float4*)(bg + l * 40 + f0);
            float acc0[4] = {bgv[0], bgv[1], bgv[2], bgv[3]};
            float acc1[4] = {bgv[0], bgv[1], bgv[2], bgv[3]};
            #pragma unroll
            for (int j4 = 0; j4 < 40; j4 += 4) {
                float c0a[4], c1a[4];
                *(float4*)c0a = *(float4*)(comp + n0 * SC + j4);
                *(float4*)c1a = *(float4*)(comp + n0 * SC + SC + j4);
                #pragma unroll
                for (int u = 0; u < 4; ++u) {
                    float wv[4];
                    *(float4*)wv = *(const float4*)(wgl + (j4 + u) * 40 + f0);
                    #pragma unroll
                    for (int q = 0; q < 4; ++q) {
                        acc0[q] = fmaf(c0a[u], wv[q], acc0[q]);
                        acc1[q] = fmaf(c1a[u], wv[q], acc1[q]);
                    }
                }
            }
            float h0[4], h1[4];
            #pragma unroll
            for (int q = 0; q < 4; ++q) {
                h0[q] = acc0[q] > 0.f ? acc0[q] : 0.01f * acc0[q];
                h1[q] = acc1[q] > 0.f ? acc1[q] : 0.01f * acc1[q];
            }
            *(float4*)(h_s + n0 * SC + f0) = *(float4*)h0;
            *(float4*)(h_s + n0 * SC + SC + f0) = *(float4*)h1;
        }
        __syncthreads();
        if (act) {
            // ---- m2: comp += A @ h (A and h from LDS) ----
            float acc0[4] = {0, 0, 0, 0}, acc1[4] = {0, 0, 0, 0};
            #pragma unroll
            for (int m4 = 0; m4 < 48; m4 += 4) {
                float a0a[4], a1a[4];
                *(float4*)a0a = *(float4*)(a_s + n0 * SA + m4);
                *(float4*)a1a = *(float4*)(a_s + n0 * SA + SA + m4);
                #pragma unroll
                for (int u = 0; u < 4; ++u) {
                    float hv[4];
                    *(float4*)hv = *(float4*)(h_s + (m4 + u) * SC + f0);
                    #pragma unroll
                    for (int q = 0; q < 4; ++q) {
                        acc0[q] = fmaf(a0a[u], hv[q], acc0[q]);
                        acc1[q] = fmaf(a1a[u], hv[q], acc1[q]);
                    }
                }
            }
            #pragma unroll
            for (int m = 48; m < 50; ++m) {
                const float a0 = a_s[n0 * SA + m], a1 = a_s[n0 * SA + SA + m];
                float hv[4];
                *(float4*)hv = *(float4*)(h_s + m * SC + f0);
                #pragma unroll
                for (int q = 0; q < 4; ++q) {
                    acc0[q] = fmaf(a0, hv[q], acc0[q]);
                    acc1[q] = fmaf(a1, hv[q], acc1[q]);
                }
            }
            float c0a[4], c1a[4];
            *(float4*)c0a = *(float4*)(comp + n0 * SC + f0);
            *(float4*)c1a = *(float4*)(comp + n0 * SC + SC + f0);
            #pragma unroll
            for (int q = 0; q < 4; ++q) { c0a[q] += acc0[q]; c1a[q] += acc1[q]; }
            *(float4*)(comp + n0 * SC + f0) = *(float4*)c0a;
            *(float4*)(comp + n0 * SC + SC + f0) = *(float4*)c1a;
        }
        __syncthreads();
    }
    if (tid < 40) {
        float s = res_sum;
        for (int n = 0; n < 50; ++n) s += comp[n * SC + tid];
        ws_cv[(size_t)b * 40 + tid] = s * 0.02f;
    }
}

// ===================== k_tail (control) =====================
__global__ __launch_bounds__(256) void k_tail(
    const float* __restrict__ protein, const float* __restrict__ b2,
    const float* __restrict__ W3, const float* __restrict__ b3,
    const float* __restrict__ Wp, const float* __restrict__ bp,
    const float* __restrict__ Watt, const float* __restrict__ batt,
    const float* __restrict__ Wm, const float* __restrict__ bm,
    const float* __restrict__ Wo, const float* __restrict__ bo,
    const float* __restrict__ ws_cv, const float* __restrict__ ws_part,
    float* __restrict__ out)
{
    const int G = 8, PC = 520;
    __shared__ float pc[8 * 520];
    __shared__ float p40s[8 * 40];
    __shared__ float phs[8 * 40];
    __shared__ float wts[8];
    __shared__ float cps[2][8 * 84];
    const int tid  = threadIdx.x;
    const int lane = tid & 63, wv = tid >> 6;
    const int b0   = blockIdx.x * G;
    const int c0   = lane * 4;

    if (wv < 2) {
        float acc[4][4];
        #pragma unroll
        for (int s = 0; s < 4; ++s)
            #pragma unroll
            for (int c = 0; c < 4; ++c) acc[s][c] = 0.f;
        const float* prot = protein + (size_t)(b0 + wv * 4) * 512;
        for (int j4 = 0; j4 < 128; ++j4) {
            float pv[4][4];
            #pragma unroll
            for (int s = 0; s < 4; ++s)
                *(float4*)pv[s] = *(const float4*)(prot + (size_t)s * 512 + j4 * 4);
            #pragma unroll
            for (int u = 0; u < 4; ++u) {
                float w3v[4];
                *(float4*)w3v = *(const float4*)(W3 + (size_t)(j4 * 4 + u) * 256 + c0);
                #pragma unroll
                for (int s = 0; s < 4; ++s)
                    #pragma unroll
                    for (int c = 0; c < 4; ++c)
                        acc[s][c] = fmaf(pv[s][u], w3v[c], acc[s][c]);
            }
        }
        float b3v[4];
        *(float4*)b3v = *(const float4*)(b3 + c0);
        #pragma unroll
        for (int s = 0; s < 4; ++s) {
            float o[4];
            #pragma unroll
            for (int c = 0; c < 4; ++c) o[c] = acc[s][c] + b3v[c];
            *(float4*)(pc + (wv * 4 + s) * PC + 256 + c0) = *(float4*)o;
        }
    } else {
        const int sbase = (wv - 2) * 4;
        float b2v[4];
        *(float4*)b2v = *(const float4*)(b2 + c0);
        #pragma unroll
        for (int s = 0; s < 4; ++s) {
            float o[4] = {b2v[0], b2v[1], b2v[2], b2v[3]};
            #pragma unroll
            for (int kc = 0; kc < 8; ++kc) {
                float pv[4];
                *(float4*)pv = *(const float4*)(ws_part + ((size_t)kc * BATCH + b0 + sbase + s) * 256 + c0);
                #pragma unroll
                for (int c = 0; c < 4; ++c) o[c] += pv[c];
            }
            *(float4*)(pc + (sbase + s) * PC + c0) = *(float4*)o;
        }
    }
    __syncthreads();

    if (tid < 40) {
        const int f8 = tid >> 3, g = tid & 7, fo = f8 * 8;
        float a8[8];
        #pragma unroll
        for (int c = 0; c < 8; ++c) a8[c] = bp[fo + c];
        for (int j4 = 0; j4 < 128; ++j4) {
            float pv[4];
            *(float4*)pv = *(float4*)(pc + g * PC + j4 * 4);
            #pragma unroll
            for (int u = 0; u < 4; ++u) {
                const int j = j4 * 4 + u;
                float wa[4], wb[4];
                *(float4*)wa = *(const float4*)(Wp + j * 40 + fo);
                *(float4*)wb = *(const float4*)(Wp + j * 40 + fo + 4);
                #pragma unroll
                for (int c = 0; c < 4; ++c) {
                    a8[c]     = fmaf(pv[u], wa[c], a8[c]);
                    a8[4 + c] = fmaf(pv[u], wb[c], a8[4 + c]);
                }
            }
        }
        *(float4*)(p40s + g * 40 + fo)     = *(float4*)a8;
        *(float4*)(p40s + g * 40 + fo + 4) = *(float4*)(a8 + 4);
    }
    __syncthreads();

    for (int it = tid; it < G * 40; it += 256) {
        const int g = it / 40, f = it - g * 40;
        float s = batt[f];
        #pragma unroll
        for (int j4 = 0; j4 < 10; ++j4) {
            float pv[4];
            *(float4*)pv = *(float4*)(p40s + g * 40 + j4 * 4);
            #pragma unroll
            for (int u = 0; u < 4; ++u)
                s = fmaf(pv[u], Watt[(j4 * 4 + u) * 40 + f], s);
        }
        phs[it] = s > 0.f ? s : 0.f;
    }
    __syncthreads();

    if (tid < G) {
        float m = 0.f;
        #pragma unroll
        for (int f4 = 0; f4 < 10; ++f4) {
            float cv[4], ph[4];
            *(float4*)cv = *(const float4*)(ws_cv + (size_t)(b0 + tid) * 40 + f4 * 4);
            *(float4*)ph = *(float4*)(phs + tid * 40 + f4 * 4);
            #pragma unroll
            for (int c = 0; c < 4; ++c) m = fmaf(cv[c], ph[c], m);
        }
        wts[tid] = tanhf(m);
    }
    __syncthreads();

    for (int it = tid; it < G * 80; it += 256) {
        const int g = it / 80, f = it - g * 80;
        const float v = (f < 40) ? ws_cv[(size_t)(b0 + g) * 40 + f]
                                 : wts[g] * phs[g * 40 + (f - 40)];
        cps[0][g * 84 + f] = v;
    }
    __syncthreads();

    int cb = 0;
    for (int l = 0; l < 2; ++l) {
        for (int it = tid; it < G * 80; it += 256) {
            const int g = it / 80, kk = it - g * 80;
            float s = bm[l * 80 + kk];
            #pragma unroll
            for (int j4 = 0; j4 < 20; ++j4) {
                float cv[4];
                *(float4*)cv = *(float4*)(cps[cb] + g * 84 + j4 * 4);
                #pragma unroll
                for (int u = 0; u < 4; ++u)
                    s = fmaf(cv[u], Wm[l * 6400 + (j4 * 4 + u) * 80 + kk], s);
            }
            cps[cb ^ 1][g * 84 + kk] = s > 0.f ? s : 0.f;
        }
        __syncthreads();
        cb ^= 1;
    }
    if (tid < G) {
        float s = bo[0];
        #pragma unroll
        for (int j4 = 0; j4 < 20; ++j4) {
            float cv[4], wo[4];
            *(float4*)cv = *(float4*)(cps[cb] + tid * 84 + j4 * 4);
            *(float4*)wo = *(const float4*)(Wo + j4 * 4);
            #pragma unroll
            for (int u = 0; u < 4; ++u) s = fmaf(cv[u], wo[u], s);
        }
        out[b0 + tid] = s;
    }
}

extern "C" void kernel_launch(void* const* d_in, const int* in_sizes, int n_in,
                              void* d_out, int out_size, void* d_ws, size_t ws_size,
                              hipStream_t stream) {
    const int*   atoms   = (const int*)d_in[0];
    const float* A       = (const float*)d_in[1];
    const float* A69     = (const float*)d_in[2];
    const float* protein = (const float*)d_in[3];
    const float* emb     = (const float*)d_in[4];
    const float* Wg      = (const float*)d_in[5];
    const float* bg      = (const float*)d_in[6];
    const float* Watt    = (const float*)d_in[7];
    const float* batt    = (const float*)d_in[8];
    const float* W1      = (const float*)d_in[9];
    const float* b1      = (const float*)d_in[10];
    const float* W2      = (const float*)d_in[11];
    const float* b2      = (const float*)d_in[12];
    const float* W3      = (const float*)d_in[13];
    const float* b3      = (const float*)d_in[14];
    const float* Wp      = (const float*)d_in[15];
    const float* bp      = (const float*)d_in[16];
    const float* Wm      = (const float*)d_in[17];
    const float* bm      = (const float*)d_in[18];
    const float* Wo      = (const float*)d_in[19];
    const float* bo      = (const float*)d_in[20];

    float* ws_cv   = (float*)d_ws;                  // [4096][40]
    float* ws_part = ws_cv + (size_t)BATCH * 40;    // [8][4096][256]
    float* outp    = (float*)d_out;

    k_stream<<<dim3(4096), dim3(256), 0, stream>>>(A69, W1, b1, W2, ws_part);
    k_gnn<<<dim3(BATCH), dim3(256), 0, stream>>>(atoms, A, emb, Wg, bg, ws_cv);
    k_tail<<<dim3(512), dim3(256), 0, stream>>>(
        protein, b2, W3, b3, Wp, bp, Watt, batt, Wm, bm, Wo, bo,
        ws_cv, ws_part, outp);
}

// Round 12
// 354.686 us; speedup vs baseline: 1.1942x; 1.0668x over previous
//
#include <hip/hip_runtime.h>
#include <hip/hip_bf16.h>
#include <math.h>

// GanDTI forward. B=4096, N_ATOMS=50, FEAT=40, GNN_DEPTH=3, MLP_DEPTH=2.
//
//  k_stream: 4352 blocks x 256 thr.
//    blocks [0,256):   p256 = protein @ W3 + b3 (16 samples/block, 4/wave) ->
//                      ws_p256. L2/VALU-bound; overlaps the HBM-bound stream.
//    blocks [256,4352): partial a256 (r8 body): 8 samples x 128-k chunk.
//  k_gnn: 2048 blocks x 256 thr, TWO samples/block (2 waves each, 125 thr:
//    25 row-pairs x 5 col-groups, 2x8 tile). LDS = comp+h only (35.2 KB ->
//    4 blocks/CU = 4 waves/SIMD). A and Wg from global (L1/L2).
//  k_tail: 512 blocks x 256 thr. Phase 0: all waves reduce a256 partials and
//    fetch ws_p256 (2 samples/wave). Then p40/attention/MLP (r8 code).

#define BATCH 4096
#define SC 44

// ===================== k_stream (+p256 blocks) =====================
__global__ __launch_bounds__(256) void k_stream(
    const float* __restrict__ A69, const float* __restrict__ W1,
    const float* __restrict__ b1, const float* __restrict__ W2,
    const float* __restrict__ protein, const float* __restrict__ W3,
    const float* __restrict__ b3,
    float* __restrict__ ws_part, float* __restrict__ ws_p256)
{
    __shared__ float a69s[64 * 10];
    const int tid  = threadIdx.x;
    const int lane = tid & 63, wv = tid >> 6;
    const int c0 = lane * 4;

    if (blockIdx.x < 256) {
        // ---------- p256: 16 samples/block, 4 per wave ----------
        const int b0 = blockIdx.x * 16 + wv * 4;
        float acc[4][4];
        #pragma unroll
        for (int s = 0; s < 4; ++s)
            #pragma unroll
            for (int c = 0; c < 4; ++c) acc[s][c] = 0.f;
        const float* prot = protein + (size_t)b0 * 512;
        for (int j4 = 0; j4 < 128; ++j4) {
            float pv[4][4];
            #pragma unroll
            for (int s = 0; s < 4; ++s)
                *(float4*)pv[s] = *(const float4*)(prot + (size_t)s * 512 + j4 * 4);
            #pragma unroll
            for (int u = 0; u < 4; ++u) {
                float w3v[4];
                *(float4*)w3v = *(const float4*)(W3 + (size_t)(j4 * 4 + u) * 256 + c0);
                #pragma unroll
                for (int s = 0; s < 4; ++s)
                    #pragma unroll
                    for (int c = 0; c < 4; ++c)
                        acc[s][c] = fmaf(pv[s][u], w3v[c], acc[s][c]);
            }
        }
        float b3v[4];
        *(float4*)b3v = *(const float4*)(b3 + c0);
        #pragma unroll
        for (int s = 0; s < 4; ++s) {
            float o[4];
            #pragma unroll
            for (int c = 0; c < 4; ++c) o[c] = acc[s][c] + b3v[c];
            *(float4*)(ws_p256 + (size_t)(b0 + s) * 256 + c0) = *(float4*)o;
        }
        return;
    }

    // ---------- stream: partial a256 (r8 body) ----------
    const int sid = blockIdx.x - 256;
    const int kc = sid & 7, sg = sid >> 3;
    const int s0 = sg * 8, k0 = kc * 128;

    float w1r[30];
    #pragma unroll
    for (int k = 0; k < 15; ++k) {
        float2 t = ((const float2*)W1)[k];
        w1r[2 * k] = t.x; w1r[2 * k + 1] = t.y;
    }
    const float b1v = b1[0];

    float acc[2][4] = {{0.f,0.f,0.f,0.f},{0.f,0.f,0.f,0.f}};

    for (int h = 0; h < 2; ++h) {
        const int base = k0 + h * 64;
        const int nrh = (1001 - base < 64) ? (1001 - base) : 64;
        if (h) __syncthreads();
        for (int idx = tid; idx < 512; idx += 256) {
            const int s = idx >> 6, rr = idx & 63;
            if (rr < nrh) {
                const float2* p = (const float2*)(A69 + ((size_t)(s0 + s) * 1001 + base + rr) * 30);
                float v = b1v;
                #pragma unroll
                for (int k = 0; k < 15; ++k) {
                    float2 q = p[k];
                    v = fmaf(q.x, w1r[2 * k], v);
                    v = fmaf(q.y, w1r[2 * k + 1], v);
                }
                a69s[rr * 10 + s] = v;
            }
        }
        __syncthreads();
        for (int k = 0; k < nrh; ++k) {
            const float a0 = a69s[k * 10 + wv * 2];
            const float a1 = a69s[k * 10 + wv * 2 + 1];
            float w2v[4];
            *(float4*)w2v = *(const float4*)(W2 + (size_t)(base + k) * 256 + c0);
            #pragma unroll
            for (int c = 0; c < 4; ++c) {
                acc[0][c] = fmaf(a0, w2v[c], acc[0][c]);
                acc[1][c] = fmaf(a1, w2v[c], acc[1][c]);
            }
        }
    }
    #pragma unroll
    for (int s = 0; s < 2; ++s)
        *(float4*)(ws_part + ((size_t)kc * BATCH + s0 + wv * 2 + s) * 256 + c0) = *(float4*)acc[s];
}

// ===================== k_gnn (2 samples/block, 2x8 tile) =====================
__global__ __launch_bounds__(256) void k_gnn(
    const int* __restrict__ atoms, const float* __restrict__ A,
    const float* __restrict__ emb, const float* __restrict__ Wg,
    const float* __restrict__ bg, float* __restrict__ ws_cv)
{
    __shared__ float sm[8800];   // comp: [2][50*44] @0, h: [2][50*44] @4400
    const int tid = threadIdx.x;
    const int smp = tid >> 7;          // 0,1 = sample within block
    const int t   = tid & 127;         // thread within sample (125 active)
    const int b   = blockIdx.x * 2 + smp;

    float* comp = sm + smp * 2200;
    float* h_s  = sm + 4400 + smp * 2200;

    // stage comp = emb[atoms] for both samples (block-strided, b128)
    for (int idx = tid; idx < 1000; idx += 256) {
        const int s_ = idx / 500, rem = idx - s_ * 500;
        const int n = rem / 10, f4 = rem - n * 10;
        const int row = atoms[(blockIdx.x * 2 + s_) * 50 + n];
        *(float4*)(sm + s_ * 2200 + n * SC + f4 * 4) = *(const float4*)(emb + row * 40 + f4 * 4);
    }
    __syncthreads();

    // residual column sums (80 threads: tid<80, s_=tid/40, col=tid%40)
    float res_sum = 0.f;
    if (tid < 80) {
        const int s_ = tid / 40, col = tid - s_ * 40;
        const float* c_ = sm + s_ * 2200;
        for (int n = 0; n < 50; ++n) res_sum += c_[n * SC + col];
    }

    const int rg = t / 5;              // 0..24 (row pair)
    const int cg = t - rg * 5;         // 0..4  (8-col group)
    const int n0 = rg * 2, f0 = cg * 8;
    const bool act = (t < 125);
    const float* Ab = A + (size_t)b * 2500;

    for (int l = 0; l < 3; ++l) {
        const float* wgl = Wg + l * 1600;
        if (act) {
            // ---- m1: h = leaky(comp @ Wg[l] + bg[l]) ----
            float bgv[8];
            *(float4*)bgv       = *(const float4*)(bg + l * 40 + f0);
            *(float4*)(bgv + 4) = *(const float4*)(bg + l * 40 + f0 + 4);
            float acc0[8], acc1[8];
            #pragma unroll
            for (int c = 0; c < 8; ++c) { acc0[c] = bgv[c]; acc1[c] = bgv[c]; }
            #pragma unroll
            for (int j4 = 0; j4 < 10; ++j4) {
                float c0a[4], c1a[4];
                *(float4*)c0a = *(float4*)(comp + n0 * SC + j4 * 4);
                *(float4*)c1a = *(float4*)(comp + n0 * SC + SC + j4 * 4);
                #pragma unroll
                for (int u = 0; u < 4; ++u) {
                    float w8[8];
                    *(float4*)w8       = *(const float4*)(wgl + (j4 * 4 + u) * 40 + f0);
                    *(float4*)(w8 + 4) = *(const float4*)(wgl + (j4 * 4 + u) * 40 + f0 + 4);
                    #pragma unroll
                    for (int c = 0; c < 8; ++c) {
                        acc0[c] = fmaf(c0a[u], w8[c], acc0[c]);
                        acc1[c] = fmaf(c1a[u], w8[c], acc1[c]);
                    }
                }
            }
            float h0[8], h1[8];
            #pragma unroll
            for (int c = 0; c < 8; ++c) {
                h0[c] = acc0[c] > 0.f ? acc0[c] : 0.01f * acc0[c];
                h1[c] = acc1[c] > 0.f ? acc1[c] : 0.01f * acc1[c];
            }
            *(float4*)(h_s + n0 * SC + f0)          = *(float4*)h0;
            *(float4*)(h_s + n0 * SC + f0 + 4)      = *(float4*)(h0 + 4);
            *(float4*)(h_s + n0 * SC + SC + f0)     = *(float4*)h1;
            *(float4*)(h_s + n0 * SC + SC + f0 + 4) = *(float4*)(h1 + 4);
        }
        __syncthreads();   // h complete across the sample's 2 waves
        if (act) {
            // ---- m2: comp += A @ h (A from global; row n0 b128, n0+1 b64) ----
            float acc0[8], acc1[8];
            #pragma unroll
            for (int c = 0; c < 8; ++c) { acc0[c] = 0.f; acc1[c] = 0.f; }
            #pragma unroll
            for (int m4 = 0; m4 < 12; ++m4) {
                float a0a[4], a1a[4];
                *(float4*)a0a       = *(const float4*)(Ab + n0 * 50 + m4 * 4);
                *(float2*)a1a       = *(const float2*)(Ab + (n0 + 1) * 50 + m4 * 4);
                *(float2*)(a1a + 2) = *(const float2*)(Ab + (n0 + 1) * 50 + m4 * 4 + 2);
                #pragma unroll
                for (int u = 0; u < 4; ++u) {
                    float h8[8];
                    *(float4*)h8       = *(float4*)(h_s + (m4 * 4 + u) * SC + f0);
                    *(float4*)(h8 + 4) = *(float4*)(h_s + (m4 * 4 + u) * SC + f0 + 4);
                    #pragma unroll
                    for (int c = 0; c < 8; ++c) {
                        acc0[c] = fmaf(a0a[u], h8[c], acc0[c]);
                        acc1[c] = fmaf(a1a[u], h8[c], acc1[c]);
                    }
                }
            }
            {   // tail m = 48, 49
                float h48[8], h49[8];
                *(float4*)h48       = *(float4*)(h_s + 48 * SC + f0);
                *(float4*)(h48 + 4) = *(float4*)(h_s + 48 * SC + f0 + 4);
                *(float4*)h49       = *(float4*)(h_s + 49 * SC + f0);
                *(float4*)(h49 + 4) = *(float4*)(h_s + 49 * SC + f0 + 4);
                const float a048 = Ab[n0 * 50 + 48], a049 = Ab[n0 * 50 + 49];
                const float a148 = Ab[(n0 + 1) * 50 + 48], a149 = Ab[(n0 + 1) * 50 + 49];
                #pragma unroll
                for (int c = 0; c < 8; ++c) {
                    acc0[c] = fmaf(a048, h48[c], acc0[c]);
                    acc0[c] = fmaf(a049, h49[c], acc0[c]);
                    acc1[c] = fmaf(a148, h48[c], acc1[c]);
                    acc1[c] = fmaf(a149, h49[c], acc1[c]);
                }
            }
            float c0a[8], c1a[8];
            *(float4*)c0a       = *(float4*)(comp + n0 * SC + f0);
            *(float4*)(c0a + 4) = *(float4*)(comp + n0 * SC + f0 + 4);
            *(float4*)c1a       = *(float4*)(comp + n0 * SC + SC + f0);
            *(float4*)(c1a + 4) = *(float4*)(comp + n0 * SC + SC + f0 + 4);
            #pragma unroll
            for (int c = 0; c < 8; ++c) { c0a[c] += acc0[c]; c1a[c] += acc1[c]; }
            *(float4*)(comp + n0 * SC + f0)          = *(float4*)c0a;
            *(float4*)(comp + n0 * SC + f0 + 4)      = *(float4*)(c0a + 4);
            *(float4*)(comp + n0 * SC + SC + f0)     = *(float4*)c1a;
            *(float4*)(comp + n0 * SC + SC + f0 + 4) = *(float4*)(c1a + 4);
        }
        __syncthreads();
    }

    // mean over atoms + residual
    if (tid < 80) {
        const int s_ = tid / 40, col = tid - s_ * 40;
        const float* c_ = sm + s_ * 2200;
        float s = res_sum;
        for (int n = 0; n < 50; ++n) s += c_[n * SC + col];
        ws_cv[(size_t)(blockIdx.x * 2 + s_) * 40 + col] = s * 0.02f;
    }
}

// ===================== k_tail =====================
__global__ __launch_bounds__(256) void k_tail(
    const float* __restrict__ b2,
    const float* __restrict__ Wp, const float* __restrict__ bp,
    const float* __restrict__ Watt, const float* __restrict__ batt,
    const float* __restrict__ Wm, const float* __restrict__ bm,
    const float* __restrict__ Wo, const float* __restrict__ bo,
    const float* __restrict__ ws_cv, const float* __restrict__ ws_part,
    const float* __restrict__ ws_p256, float* __restrict__ out)
{
    const int G = 8, PC = 520;
    __shared__ float pc[8 * 520];
    __shared__ float p40s[8 * 40];
    __shared__ float phs[8 * 40];
    __shared__ float wts[8];
    __shared__ float cps[2][8 * 84];
    const int tid  = threadIdx.x;
    const int lane = tid & 63, wv = tid >> 6;
    const int b0   = blockIdx.x * G;
    const int c0   = lane * 4;

    // ---- phase 0: a256 reduce + p256 fetch, 2 samples per wave ----
    {
        float b2v[4];
        *(float4*)b2v = *(const float4*)(b2 + c0);
        #pragma unroll
        for (int s = 0; s < 2; ++s) {
            const int g = wv * 2 + s;
            float o[4] = {b2v[0], b2v[1], b2v[2], b2v[3]};
            #pragma unroll
            for (int kc = 0; kc < 8; ++kc) {
                float pv[4];
                *(float4*)pv = *(const float4*)(ws_part + ((size_t)kc * BATCH + b0 + g) * 256 + c0);
                #pragma unroll
                for (int c = 0; c < 4; ++c) o[c] += pv[c];
            }
            *(float4*)(pc + g * PC + c0) = *(float4*)o;
            *(float4*)(pc + g * PC + 256 + c0) =
                *(const float4*)(ws_p256 + (size_t)(b0 + g) * 256 + c0);
        }
    }
    __syncthreads();

    if (tid < 40) {
        const int f8 = tid >> 3, g = tid & 7, fo = f8 * 8;
        float a8[8];
        #pragma unroll
        for (int c = 0; c < 8; ++c) a8[c] = bp[fo + c];
        for (int j4 = 0; j4 < 128; ++j4) {
            float pv[4];
            *(float4*)pv = *(float4*)(pc + g * PC + j4 * 4);
            #pragma unroll
            for (int u = 0; u < 4; ++u) {
                const int j = j4 * 4 + u;
                float wa[4], wb[4];
                *(float4*)wa = *(const float4*)(Wp + j * 40 + fo);
                *(float4*)wb = *(const float4*)(Wp + j * 40 + fo + 4);
                #pragma unroll
                for (int c = 0; c < 4; ++c) {
                    a8[c]     = fmaf(pv[u], wa[c], a8[c]);
                    a8[4 + c] = fmaf(pv[u], wb[c], a8[4 + c]);
                }
            }
        }
        *(float4*)(p40s + g * 40 + fo)     = *(float4*)a8;
        *(float4*)(p40s + g * 40 + fo + 4) = *(float4*)(a8 + 4);
    }
    __syncthreads();

    for (int it = tid; it < G * 40; it += 256) {
        const int g = it / 40, f = it - g * 40;
        float s = batt[f];
        #pragma unroll
        for (int j4 = 0; j4 < 10; ++j4) {
            float pv[4];
            *(float4*)pv = *(float4*)(p40s + g * 40 + j4 * 4);
            #pragma unroll
            for (int u = 0; u < 4; ++u)
                s = fmaf(pv[u], Watt[(j4 * 4 + u) * 40 + f], s);
        }
        phs[it] = s > 0.f ? s : 0.f;
    }
    __syncthreads();

    if (tid < G) {
        float m = 0.f;
        #pragma unroll
        for (int f4 = 0; f4 < 10; ++f4) {
            float cv[4], ph[4];
            *(float4*)cv = *(const float4*)(ws_cv + (size_t)(b0 + tid) * 40 + f4 * 4);
            *(float4*)ph = *(float4*)(phs + tid * 40 + f4 * 4);
            #pragma unroll
            for (int c = 0; c < 4; ++c) m = fmaf(cv[c], ph[c], m);
        }
        wts[tid] = tanhf(m);
    }
    __syncthreads();

    for (int it = tid; it < G * 80; it += 256) {
        const int g = it / 80, f = it - g * 80;
        const float v = (f < 40) ? ws_cv[(size_t)(b0 + g) * 40 + f]
                                 : wts[g] * phs[g * 40 + (f - 40)];
        cps[0][g * 84 + f] = v;
    }
    __syncthreads();

    int cb = 0;
    for (int l = 0; l < 2; ++l) {
        for (int it = tid; it < G * 80; it += 256) {
            const int g = it / 80, kk = it - g * 80;
            float s = bm[l * 80 + kk];
            #pragma unroll
            for (int j4 = 0; j4 < 20; ++j4) {
                float cv[4];
                *(float4*)cv = *(float4*)(cps[cb] + g * 84 + j4 * 4);
                #pragma unroll
                for (int u = 0; u < 4; ++u)
                    s = fmaf(cv[u], Wm[l * 6400 + (j4 * 4 + u) * 80 + kk], s);
            }
            cps[cb ^ 1][g * 84 + kk] = s > 0.f ? s : 0.f;
        }
        __syncthreads();
        cb ^= 1;
    }
    if (tid < G) {
        float s = bo[0];
        #pragma unroll
        for (int j4 = 0; j4 < 20; ++j4) {
            float cv[4], wo[4];
            *(float4*)cv = *(float4*)(cps[cb] + tid * 84 + j4 * 4);
            *(float4*)wo = *(const float4*)(Wo + j4 * 4);
            #pragma unroll
            for (int u = 0; u < 4; ++u) s = fmaf(cv[u], wo[u], s);
        }
        out[b0 + tid] = s;
    }
}

extern "C" void kernel_launch(void* const* d_in, const int* in_sizes, int n_in,
                              void* d_out, int out_size, void* d_ws, size_t ws_size,
                              hipStream_t stream) {
    const int*   atoms   = (const int*)d_in[0];
    const float* A       = (const float*)d_in[1];
    const float* A69     = (const float*)d_in[2];
    const float* protein = (const float*)d_in[3];
    const float* emb     = (const float*)d_in[4];
    const float* Wg      = (const float*)d_in[5];
    const float* bg      = (const float*)d_in[6];
    const float* Watt    = (const float*)d_in[7];
    const float* batt    = (const float*)d_in[8];
    const float* W1      = (const float*)d_in[9];
    const float* b1      = (const float*)d_in[10];
    const float* W2      = (const float*)d_in[11];
    const float* b2      = (const float*)d_in[12];
    const float* W3      = (const float*)d_in[13];
    const float* b3      = (const float*)d_in[14];
    const float* Wp      = (const float*)d_in[15];
    const float* bp      = (const float*)d_in[16];
    const float* Wm      = (const float*)d_in[17];
    const float* bm      = (const float*)d_in[18];
    const float* Wo      = (const float*)d_in[19];
    const float* bo      = (const float*)d_in[20];

    float* ws_cv   = (float*)d_ws;                           // [4096][40]
    float* ws_part = ws_cv + (size_t)BATCH * 40;             // [8][4096][256]
    float* ws_p256 = ws_part + (size_t)8 * BATCH * 256;      // [4096][256]
    float* outp    = (float*)d_out;

    k_stream<<<dim3(4352), dim3(256), 0, stream>>>(
        A69, W1, b1, W2, protein, W3, b3, ws_part, ws_p256);
    k_gnn<<<dim3(2048), dim3(256), 0, stream>>>(atoms, A, emb, Wg, bg, ws_cv);
    k_tail<<<dim3(512), dim3(256), 0, stream>>>(
        b2, Wp, bp, Watt, batt, Wm, bm, Wo, bo,
        ws_cv, ws_part, ws_p256, outp);
}

// Round 13
// 320.399 us; speedup vs baseline: 1.3219x; 1.1070x over previous
//
#include <hip/hip_runtime.h>
#include <hip/hip_bf16.h>
#include <math.h>

// GanDTI forward. B=4096, N_ATOMS=50, FEAT=40, GNN_DEPTH=3, MLP_DEPTH=2.
//
// k_main: 6528 blocks x 256 thr, heterogeneous fusion of r12's proven parts:
//   blk%3==0 -> GNN job blk/3 (2048 used of 2176): 2 samples/block, 2x8 tile,
//               comp+h LDS (35.2 KB), A/Wg from global.  [r12 k_gnn verbatim]
//   else     -> stream job sid = blk - blk/3 - 1 (0..4351):
//               sid<256: p256 = protein@W3+b3 (16 samples);
//               else:    partial a256 chunk (8 samples x 128 k). [r12 verbatim]
//   Rationale: GNN is LDS-port/VALU-bound, stream is HBM-bound ->
//   co-residency overlaps the two serial phases.
// k_tail: 1024 blocks x 256 thr, 4 samples/block (2x parallelism vs r12),
//   p40 over 160 threads (b128 LDS + coalesced Wp).

#define BATCH 4096
#define SC 44

// ===================== k_main =====================
__global__ __launch_bounds__(256) void k_main(
    const int* __restrict__ atoms, const float* __restrict__ A,
    const float* __restrict__ A69, const float* __restrict__ emb,
    const float* __restrict__ Wg, const float* __restrict__ bg,
    const float* __restrict__ W1, const float* __restrict__ b1,
    const float* __restrict__ W2,
    const float* __restrict__ protein, const float* __restrict__ W3,
    const float* __restrict__ b3,
    float* __restrict__ ws_cv, float* __restrict__ ws_part,
    float* __restrict__ ws_p256)
{
    __shared__ float sm[8800];
    const int tid  = threadIdx.x;
    const int blk  = blockIdx.x;
    const int lane = tid & 63, wv = tid >> 6;
    const int c0   = lane * 4;

    if (blk % 3 != 0) {
        const int sid = blk - blk / 3 - 1;    // 0..4351
        if (sid < 256) {
            // ---------- p256: 16 samples/block, 4 per wave ----------
            const int b0 = sid * 16 + wv * 4;
            float acc[4][4];
            #pragma unroll
            for (int s = 0; s < 4; ++s)
                #pragma unroll
                for (int c = 0; c < 4; ++c) acc[s][c] = 0.f;
            const float* prot = protein + (size_t)b0 * 512;
            for (int j4 = 0; j4 < 128; ++j4) {
                float pv[4][4];
                #pragma unroll
                for (int s = 0; s < 4; ++s)
                    *(float4*)pv[s] = *(const float4*)(prot + (size_t)s * 512 + j4 * 4);
                #pragma unroll
                for (int u = 0; u < 4; ++u) {
                    float w3v[4];
                    *(float4*)w3v = *(const float4*)(W3 + (size_t)(j4 * 4 + u) * 256 + c0);
                    #pragma unroll
                    for (int s = 0; s < 4; ++s)
                        #pragma unroll
                        for (int c = 0; c < 4; ++c)
                            acc[s][c] = fmaf(pv[s][u], w3v[c], acc[s][c]);
                }
            }
            float b3v[4];
            *(float4*)b3v = *(const float4*)(b3 + c0);
            #pragma unroll
            for (int s = 0; s < 4; ++s) {
                float o[4];
                #pragma unroll
                for (int c = 0; c < 4; ++c) o[c] = acc[s][c] + b3v[c];
                *(float4*)(ws_p256 + (size_t)(b0 + s) * 256 + c0) = *(float4*)o;
            }
            return;
        }
        // ---------- stream: partial a256, 8 samples x 128-k chunk ----------
        const int cid = sid - 256;
        const int kc = cid & 7, sg = cid >> 3;
        const int s0 = sg * 8, k0 = kc * 128;
        float* a69s = sm;    // [64][10]

        float w1r[30];
        #pragma unroll
        for (int k = 0; k < 15; ++k) {
            float2 t = ((const float2*)W1)[k];
            w1r[2 * k] = t.x; w1r[2 * k + 1] = t.y;
        }
        const float b1v = b1[0];

        float acc[2][4] = {{0.f,0.f,0.f,0.f},{0.f,0.f,0.f,0.f}};

        for (int h = 0; h < 2; ++h) {
            const int base = k0 + h * 64;
            const int nrh = (1001 - base < 64) ? (1001 - base) : 64;
            if (h) __syncthreads();
            for (int idx = tid; idx < 512; idx += 256) {
                const int s = idx >> 6, rr = idx & 63;
                if (rr < nrh) {
                    const float2* p = (const float2*)(A69 + ((size_t)(s0 + s) * 1001 + base + rr) * 30);
                    float v = b1v;
                    #pragma unroll
                    for (int k = 0; k < 15; ++k) {
                        float2 q = p[k];
                        v = fmaf(q.x, w1r[2 * k], v);
                        v = fmaf(q.y, w1r[2 * k + 1], v);
                    }
                    a69s[rr * 10 + s] = v;
                }
            }
            __syncthreads();
            for (int k = 0; k < nrh; ++k) {
                const float a0 = a69s[k * 10 + wv * 2];
                const float a1 = a69s[k * 10 + wv * 2 + 1];
                float w2v[4];
                *(float4*)w2v = *(const float4*)(W2 + (size_t)(base + k) * 256 + c0);
                #pragma unroll
                for (int c = 0; c < 4; ++c) {
                    acc[0][c] = fmaf(a0, w2v[c], acc[0][c]);
                    acc[1][c] = fmaf(a1, w2v[c], acc[1][c]);
                }
            }
        }
        #pragma unroll
        for (int s = 0; s < 2; ++s)
            *(float4*)(ws_part + ((size_t)kc * BATCH + s0 + wv * 2 + s) * 256 + c0) = *(float4*)acc[s];
        return;
    }

    // ================= GNN: r12 body, job = blk/3 =================
    const int job = blk / 3;
    if (job >= 2048) return;
    const int smp = tid >> 7;
    const int t   = tid & 127;
    const int b   = job * 2 + smp;

    float* comp = sm + smp * 2200;
    float* h_s  = sm + 4400 + smp * 2200;

    for (int idx = tid; idx < 1000; idx += 256) {
        const int s_ = idx / 500, rem = idx - s_ * 500;
        const int n = rem / 10, f4 = rem - n * 10;
        const int row = atoms[(job * 2 + s_) * 50 + n];
        *(float4*)(sm + s_ * 2200 + n * SC + f4 * 4) = *(const float4*)(emb + row * 40 + f4 * 4);
    }
    __syncthreads();

    float res_sum = 0.f;
    if (tid < 80) {
        const int s_ = tid / 40, col = tid - s_ * 40;
        const float* c_ = sm + s_ * 2200;
        for (int n = 0; n < 50; ++n) res_sum += c_[n * SC + col];
    }

    const int rg = t / 5;
    const int cg = t - rg * 5;
    const int n0 = rg * 2, f0 = cg * 8;
    const bool act = (t < 125);
    const float* Ab = A + (size_t)b * 2500;

    for (int l = 0; l < 3; ++l) {
        const float* wgl = Wg + l * 1600;
        if (act) {
            float bgv[8];
            *(float4*)bgv       = *(const float4*)(bg + l * 40 + f0);
            *(float4*)(bgv + 4) = *(const float4*)(bg + l * 40 + f0 + 4);
            float acc0[8], acc1[8];
            #pragma unroll
            for (int c = 0; c < 8; ++c) { acc0[c] = bgv[c]; acc1[c] = bgv[c]; }
            #pragma unroll
            for (int j4 = 0; j4 < 10; ++j4) {
                float c0a[4], c1a[4];
                *(float4*)c0a = *(float4*)(comp + n0 * SC + j4 * 4);
                *(float4*)c1a = *(float4*)(comp + n0 * SC + SC + j4 * 4);
                #pragma unroll
                for (int u = 0; u < 4; ++u) {
                    float w8[8];
                    *(float4*)w8       = *(const float4*)(wgl + (j4 * 4 + u) * 40 + f0);
                    *(float4*)(w8 + 4) = *(const float4*)(wgl + (j4 * 4 + u) * 40 + f0 + 4);
                    #pragma unroll
                    for (int c = 0; c < 8; ++c) {
                        acc0[c] = fmaf(c0a[u], w8[c], acc0[c]);
                        acc1[c] = fmaf(c1a[u], w8[c], acc1[c]);
                    }
                }
            }
            float h0[8], h1[8];
            #pragma unroll
            for (int c = 0; c < 8; ++c) {
                h0[c] = acc0[c] > 0.f ? acc0[c] : 0.01f * acc0[c];
                h1[c] = acc1[c] > 0.f ? acc1[c] : 0.01f * acc1[c];
            }
            *(float4*)(h_s + n0 * SC + f0)          = *(float4*)h0;
            *(float4*)(h_s + n0 * SC + f0 + 4)      = *(float4*)(h0 + 4);
            *(float4*)(h_s + n0 * SC + SC + f0)     = *(float4*)h1;
            *(float4*)(h_s + n0 * SC + SC + f0 + 4) = *(float4*)(h1 + 4);
        }
        __syncthreads();
        if (act) {
            float acc0[8], acc1[8];
            #pragma unroll
            for (int c = 0; c < 8; ++c) { acc0[c] = 0.f; acc1[c] = 0.f; }
            #pragma unroll
            for (int m4 = 0; m4 < 12; ++m4) {
                float a0a[4], a1a[4];
                *(float4*)a0a       = *(const float4*)(Ab + n0 * 50 + m4 * 4);
                *(float2*)a1a       = *(const float2*)(Ab + (n0 + 1) * 50 + m4 * 4);
                *(float2*)(a1a + 2) = *(const float2*)(Ab + (n0 + 1) * 50 + m4 * 4 + 2);
                #pragma unroll
                for (int u = 0; u < 4; ++u) {
                    float h8[8];
                    *(float4*)h8       = *(float4*)(h_s + (m4 * 4 + u) * SC + f0);
                    *(float4*)(h8 + 4) = *(float4*)(h_s + (m4 * 4 + u) * SC + f0 + 4);
                    #pragma unroll
                    for (int c = 0; c < 8; ++c) {
                        acc0[c] = fmaf(a0a[u], h8[c], acc0[c]);
                        acc1[c] = fmaf(a1a[u], h8[c], acc1[c]);
                    }
                }
            }
            {
                float h48[8], h49[8];
                *(float4*)h48       = *(float4*)(h_s + 48 * SC + f0);
                *(float4*)(h48 + 4) = *(float4*)(h_s + 48 * SC + f0 + 4);
                *(float4*)h49       = *(float4*)(h_s + 49 * SC + f0);
                *(float4*)(h49 + 4) = *(float4*)(h_s + 49 * SC + f0 + 4);
                const float a048 = Ab[n0 * 50 + 48], a049 = Ab[n0 * 50 + 49];
                const float a148 = Ab[(n0 + 1) * 50 + 48], a149 = Ab[(n0 + 1) * 50 + 49];
                #pragma unroll
                for (int c = 0; c < 8; ++c) {
                    acc0[c] = fmaf(a048, h48[c], acc0[c]);
                    acc0[c] = fmaf(a049, h49[c], acc0[c]);
                    acc1[c] = fmaf(a148, h48[c], acc1[c]);
                    acc1[c] = fmaf(a149, h49[c], acc1[c]);
                }
            }
            float c0a[8], c1a[8];
            *(float4*)c0a       = *(float4*)(comp + n0 * SC + f0);
            *(float4*)(c0a + 4) = *(float4*)(comp + n0 * SC + f0 + 4);
            *(float4*)c1a       = *(float4*)(comp + n0 * SC + SC + f0);
            *(float4*)(c1a + 4) = *(float4*)(comp + n0 * SC + SC + f0 + 4);
            #pragma unroll
            for (int c = 0; c < 8; ++c) { c0a[c] += acc0[c]; c1a[c] += acc1[c]; }
            *(float4*)(comp + n0 * SC + f0)          = *(float4*)c0a;
            *(float4*)(comp + n0 * SC + f0 + 4)      = *(float4*)(c0a + 4);
            *(float4*)(comp + n0 * SC + SC + f0)     = *(float4*)c1a;
            *(float4*)(comp + n0 * SC + SC + f0 + 4) = *(float4*)(c1a + 4);
        }
        __syncthreads();
    }

    if (tid < 80) {
        const int s_ = tid / 40, col = tid - s_ * 40;
        const float* c_ = sm + s_ * 2200;
        float s = res_sum;
        for (int n = 0; n < 50; ++n) s += c_[n * SC + col];
        ws_cv[(size_t)(job * 2 + s_) * 40 + col] = s * 0.02f;
    }
}

// ===================== k_tail (G=4, 1024 blocks) =====================
__global__ __launch_bounds__(256) void k_tail(
    const float* __restrict__ b2,
    const float* __restrict__ Wp, const float* __restrict__ bp,
    const float* __restrict__ Watt, const float* __restrict__ batt,
    const float* __restrict__ Wm, const float* __restrict__ bm,
    const float* __restrict__ Wo, const float* __restrict__ bo,
    const float* __restrict__ ws_cv, const float* __restrict__ ws_part,
    const float* __restrict__ ws_p256, float* __restrict__ out)
{
    const int G = 4, PC = 520;
    __shared__ float pc[4 * 520];
    __shared__ float p40s[4 * 40];
    __shared__ float phs[4 * 40];
    __shared__ float wts[4];
    __shared__ float cps[2][4 * 84];
    const int tid  = threadIdx.x;
    const int lane = tid & 63, wv = tid >> 6;
    const int b0   = blockIdx.x * G;
    const int c0   = lane * 4;

    // phase 0: wave wv owns sample wv — a256 reduce + p256 fetch
    {
        const int g = wv;
        float b2v[4];
        *(float4*)b2v = *(const float4*)(b2 + c0);
        float o[4] = {b2v[0], b2v[1], b2v[2], b2v[3]};
        #pragma unroll
        for (int kc = 0; kc < 8; ++kc) {
            float pv[4];
            *(float4*)pv = *(const float4*)(ws_part + ((size_t)kc * BATCH + b0 + g) * 256 + c0);
            #pragma unroll
            for (int c = 0; c < 4; ++c) o[c] += pv[c];
        }
        *(float4*)(pc + g * PC + c0) = *(float4*)o;
        *(float4*)(pc + g * PC + 256 + c0) =
            *(const float4*)(ws_p256 + (size_t)(b0 + g) * 256 + c0);
    }
    __syncthreads();

    // p40: 160 tasks (g 0..3, f 0..39); b128 LDS + coalesced Wp
    if (tid < 160) {
        const int g = tid / 40, f = tid - (tid / 40) * 40;
        float s = bp[f];
        for (int j4 = 0; j4 < 128; ++j4) {
            float pv[4];
            *(float4*)pv = *(float4*)(pc + g * PC + j4 * 4);
            #pragma unroll
            for (int u = 0; u < 4; ++u)
                s = fmaf(pv[u], Wp[(j4 * 4 + u) * 40 + f], s);
        }
        p40s[g * 40 + f] = s;
    }
    __syncthreads();

    // protein_h = relu(p40 @ Watt + batt): 160 tasks
    if (tid < 160) {
        const int g = tid / 40, f = tid - (tid / 40) * 40;
        float s = batt[f];
        #pragma unroll
        for (int j4 = 0; j4 < 10; ++j4) {
            float pv[4];
            *(float4*)pv = *(float4*)(p40s + g * 40 + j4 * 4);
            #pragma unroll
            for (int u = 0; u < 4; ++u)
                s = fmaf(pv[u], Watt[(j4 * 4 + u) * 40 + f], s);
        }
        phs[tid] = s > 0.f ? s : 0.f;
    }
    __syncthreads();

    if (tid < G) {
        float m = 0.f;
        #pragma unroll
        for (int f4 = 0; f4 < 10; ++f4) {
            float cv[4], ph[4];
            *(float4*)cv = *(const float4*)(ws_cv + (size_t)(b0 + tid) * 40 + f4 * 4);
            *(float4*)ph = *(float4*)(phs + tid * 40 + f4 * 4);
            #pragma unroll
            for (int c = 0; c < 4; ++c) m = fmaf(cv[c], ph[c], m);
        }
        wts[tid] = tanhf(m);
    }
    __syncthreads();

    for (int it = tid; it < G * 80; it += 256) {
        const int g = it / 80, f = it - (it / 80) * 80;
        const float v = (f < 40) ? ws_cv[(size_t)(b0 + g) * 40 + f]
                                 : wts[g] * phs[g * 40 + (f - 40)];
        cps[0][g * 84 + f] = v;
    }
    __syncthreads();

    int cb = 0;
    for (int l = 0; l < 2; ++l) {
        for (int it = tid; it < G * 80; it += 256) {
            const int g = it / 80, kk = it - (it / 80) * 80;
            float s = bm[l * 80 + kk];
            #pragma unroll
            for (int j4 = 0; j4 < 20; ++j4) {
                float cv[4];
                *(float4*)cv = *(float4*)(cps[cb] + g * 84 + j4 * 4);
                #pragma unroll
                for (int u = 0; u < 4; ++u)
                    s = fmaf(cv[u], Wm[l * 6400 + (j4 * 4 + u) * 80 + kk], s);
            }
            cps[cb ^ 1][g * 84 + kk] = s > 0.f ? s : 0.f;
        }
        __syncthreads();
        cb ^= 1;
    }
    if (tid < G) {
        float s = bo[0];
        #pragma unroll
        for (int j4 = 0; j4 < 20; ++j4) {
            float cv[4], wo[4];
            *(float4*)cv = *(float4*)(cps[cb] + tid * 84 + j4 * 4);
            *(float4*)wo = *(const float4*)(Wo + j4 * 4);
            #pragma unroll
            for (int u = 0; u < 4; ++u) s = fmaf(cv[u], wo[u], s);
        }
        out[b0 + tid] = s;
    }
}

extern "C" void kernel_launch(void* const* d_in, const int* in_sizes, int n_in,
                              void* d_out, int out_size, void* d_ws, size_t ws_size,
                              hipStream_t stream) {
    const int*   atoms   = (const int*)d_in[0];
    const float* A       = (const float*)d_in[1];
    const float* A69     = (const float*)d_in[2];
    const float* protein = (const float*)d_in[3];
    const float* emb     = (const float*)d_in[4];
    const float* Wg      = (const float*)d_in[5];
    const float* bg      = (const float*)d_in[6];
    const float* Watt    = (const float*)d_in[7];
    const float* batt    = (const float*)d_in[8];
    const float* W1      = (const float*)d_in[9];
    const float* b1      = (const float*)d_in[10];
    const float* W2      = (const float*)d_in[11];
    const float* b2      = (const float*)d_in[12];
    const float* W3      = (const float*)d_in[13];
    const float* b3      = (const float*)d_in[14];
    const float* Wp      = (const float*)d_in[15];
    const float* bp      = (const float*)d_in[16];
    const float* Wm      = (const float*)d_in[17];
    const float* bm      = (const float*)d_in[18];
    const float* Wo      = (const float*)d_in[19];
    const float* bo      = (const float*)d_in[20];

    float* ws_cv   = (float*)d_ws;                           // [4096][40]
    float* ws_part = ws_cv + (size_t)BATCH * 40;             // [8][4096][256]
    float* ws_p256 = ws_part + (size_t)8 * BATCH * 256;      // [4096][256]
    float* outp    = (float*)d_out;

    k_main<<<dim3(6528), dim3(256), 0, stream>>>(
        atoms, A, A69, emb, Wg, bg, W1, b1, W2, protein, W3, b3,
        ws_cv, ws_part, ws_p256);
    k_tail<<<dim3(1024), dim3(256), 0, stream>>>(
        b2, Wp, bp, Watt, batt, Wm, bm, Wo, bo,
        ws_cv, ws_part, ws_p256, outp);
}